// Round 5
// baseline (363.452 us; speedup 1.0000x reference)
//
#include <hip/hip_runtime.h>
#include <stdint.h>

#define B_ 64
#define Q_ 900
#define T_ 100
#define C_ 256
#define INF_ 1e9f
#define TCH 20      // targets per cost-kernel chunk
#define NTC 5       // T_/TCH
#define KSLOT 15    // ceil(Q_/64) column slots per lane in hung kernel
#define RG 4        // rows per warm-start group (T_ % RG == 0)

// ---------------------------------------------------------------------------
// Kernel 1: cost matrix, t-chunked for occupancy.
//   costT [B,T,Q] - coalesced scalar stores (solver layout)
//   cost  [B,Q,T] - float4 stores (output layout)
// ---------------------------------------------------------------------------
__global__ __launch_bounds__(256) void cost_kernel(
    const float* __restrict__ logits,   // [B,Q,C]
    const float* __restrict__ pboxes,   // [B,Q,4] cxcywh
    const int*   __restrict__ tlabels,  // [B,T]
    const float* __restrict__ tboxes,   // [B,T,4] cxcywh
    float* __restrict__ cost_out,       // [B,Q,T]
    float* __restrict__ costT_out)      // [B,T,Q]
{
    const int b   = blockIdx.z;
    const int t0  = blockIdx.y * TCH;
    const int tid = threadIdx.x;
    const int q   = blockIdx.x * 256 + tid;

    __shared__ float s_cx[TCH][4];
    __shared__ float s_xy[TCH][4];
    __shared__ float s_area[TCH];
    __shared__ int   s_lab[TCH];

    for (int t = tid; t < TCH; t += 256) {
        const float4 tb = *reinterpret_cast<const float4*>(tboxes + ((size_t)b * T_ + t0 + t) * 4);
        float cx = tb.x, cy = tb.y, w = tb.z, h = tb.w;
        s_cx[t][0] = cx; s_cx[t][1] = cy; s_cx[t][2] = w; s_cx[t][3] = h;
        float x0 = cx - 0.5f * w, y0 = cy - 0.5f * h;
        float x1 = cx + 0.5f * w, y1 = cy + 0.5f * h;
        s_xy[t][0] = x0; s_xy[t][1] = y0; s_xy[t][2] = x1; s_xy[t][3] = y1;
        s_area[t] = (x1 - x0) * (y1 - y0);
        s_lab[t]  = tlabels[b * T_ + t0 + t];
    }
    __syncthreads();
    if (q >= Q_) return;

    const float4 pb = *reinterpret_cast<const float4*>(pboxes + ((size_t)b * Q_ + q) * 4);
    const float pcx = pb.x, pcy = pb.y, pw = pb.z, ph = pb.w;
    const float ax0 = pcx - 0.5f * pw, ay0 = pcy - 0.5f * ph;
    const float ax1 = pcx + 0.5f * pw, ay1 = pcy + 0.5f * ph;
    const float area_a = (ax1 - ax0) * (ay1 - ay0);
    const float* __restrict__ lrow = logits + ((size_t)b * Q_ + q) * C_;

    float c[TCH];
    #pragma unroll
    for (int tt = 0; tt < TCH; ++tt) {
        float cls = -lrow[s_lab[tt]];
        float l1 = fabsf(pcx - s_cx[tt][0]) + fabsf(pcy - s_cx[tt][1])
                 + fabsf(pw  - s_cx[tt][2]) + fabsf(ph  - s_cx[tt][3]);
        float bx0 = s_xy[tt][0], by0 = s_xy[tt][1], bx1 = s_xy[tt][2], by1 = s_xy[tt][3];
        float ltx = fmaxf(ax0, bx0), lty = fmaxf(ay0, by0);
        float rbx = fminf(ax1, bx1), rby = fminf(ay1, by1);
        float wx = fmaxf(rbx - ltx, 0.0f), wy = fmaxf(rby - lty, 0.0f);
        float inter = wx * wy;
        float uni = area_a + s_area[tt] - inter;
        float iou = inter / uni;
        float ex0 = fminf(ax0, bx0), ey0 = fminf(ay0, by0);
        float ex1 = fmaxf(ax1, bx1), ey1 = fmaxf(ay1, by1);
        float ew = fmaxf(ex1 - ex0, 0.0f), eh = fmaxf(ey1 - ey0, 0.0f);
        float enc = ew * eh;
        float giou = iou - (enc - uni) / enc;
        c[tt] = cls + l1 - giou;
    }

    float* __restrict__ ct = costT_out + (size_t)b * T_ * Q_ + (size_t)t0 * Q_ + q;
    #pragma unroll
    for (int tt = 0; tt < TCH; ++tt) ct[(size_t)tt * Q_] = c[tt];

    float4* __restrict__ orow = reinterpret_cast<float4*>(cost_out + ((size_t)b * Q_ + q) * T_ + t0);
    #pragma unroll
    for (int t4 = 0; t4 < TCH / 4; ++t4)
        orow[t4] = make_float4(c[4*t4], c[4*t4+1], c[4*t4+2], c[4*t4+3]);
}

// ---------------------------------------------------------------------------
// Kernel 2: exact Hungarian (JV SAP), one wave per batch.
// Duals: u = row minima, v = 0 (round-3-proven arithmetic; NO column
// reduction — it manufactures exact-zero ties that diverge from the ref).
// Latency engineering (arithmetic-identical to round 3):
//   - wave-synchronous: volatile LDS, no __syncthreads inside the SAP loop
//     (single wave, DS ops retire in order) -> no vmcnt(0) drains
//   - next row's global loads issued right after argmin, before dual updates
//   - u[i0] via tree-start register snapshot + __shfl (rows enter a tree once)
//   - greedy assignment parallelized via LDS atomicMin + ballot (same winners:
//     smallest row index, same pend order: increasing row)
// ---------------------------------------------------------------------------
__global__ __launch_bounds__(64) void hung_kernel(
    const float* __restrict__ costT,   // [B,T,Q]
    float* __restrict__ out_pred,      // [B,T] as float
    float* __restrict__ out_tgt)       // [B,T] as float
{
    const int b = blockIdx.x;
    const int lane = threadIdx.x;
    const float* __restrict__ cb = costT + (size_t)b * T_ * Q_;

    volatile __shared__ float u[128];      // padded so u[64+lane] is in-bounds
    volatile __shared__ int   p[Q_];
    volatile __shared__ int   way[Q_];     // also greedy scratch before SAP
    volatile __shared__ int   ji[T_];
    volatile __shared__ int   pend[T_];
    __shared__ int   col[T_];

    float v[KSLOT], minv[KSLOT];

    #pragma unroll
    for (int k = 0; k < KSLOT; ++k) {
        int j = k * 64 + lane;
        if (j < Q_) { p[j] = -1; way[j] = 0x7FFFFFFF; }
        v[k] = 0.0f;
    }

    // ---- warm start: u[i] = row min, ji[i] = first argmin ----
    for (int g = 0; g < T_; g += RG) {
        float rv[RG][KSLOT];
        #pragma unroll
        for (int r = 0; r < RG; ++r) {
            const float* __restrict__ row = cb + (size_t)(g + r) * Q_;
            #pragma unroll
            for (int k = 0; k < KSLOT; ++k) {
                int j = k * 64 + lane;
                rv[r][k] = (j < Q_) ? row[j] : INF_;
            }
        }
        #pragma unroll
        for (int r = 0; r < RG; ++r) {
            float m = INF_; int mj = Q_;
            #pragma unroll
            for (int k = 0; k < KSLOT; ++k) {
                int j = k * 64 + lane;
                if (rv[r][k] < m) { m = rv[r][k]; mj = j; }   // strict <: first index
            }
            #pragma unroll
            for (int off = 1; off < 64; off <<= 1) {
                float ov = __shfl_xor(m,  off, 64);
                int   oj = __shfl_xor(mj, off, 64);
                if (ov < m || (ov == m && oj < mj)) { m = ov; mj = oj; }
            }
            if (lane == 0) { u[g + r] = m; ji[g + r] = mj; }
        }
    }
    __syncthreads();

    // ---- parallel greedy: column winner = smallest suitor row ----
    {
        int t0 = lane, t1 = lane + 64;
        if (t0 < T_) atomicMin((int*)&way[ji[t0]], t0);
        if (t1 < T_) atomicMin((int*)&way[ji[t1]], t1);
    }
    __syncthreads();
    bool lose0 = false, lose1 = false;
    {
        int t0 = lane, t1 = lane + 64;
        if (t0 < T_) {
            int j = ji[t0];
            if (way[j] == t0) p[j] = t0; else lose0 = true;
        }
        if (t1 < T_) {
            int j = ji[t1];
            if (way[j] == t1) p[j] = t1; else lose1 = true;
        }
    }
    unsigned long long m0 = __ballot(lose0);
    unsigned long long m1 = __ballot(lose1);
    const int c0 = __popcll(m0);
    if (lose0) pend[__popcll(m0 & ((1ull << lane) - 1ull))] = lane;
    if (lose1) pend[c0 + __popcll(m1 & ((1ull << lane) - 1ull))] = lane + 64;
    const int npend = c0 + __popcll(m1);
    __syncthreads();

    // ---- SAP per pending row (barrier-free inner loop) ----
    for (int kk = 0; kk < npend; ++kk) {
        const int isrc = pend[kk];
        const float u_lo = u[lane];        // tree-start snapshot
        const float u_hi = u[64 + lane];
        #pragma unroll
        for (int k = 0; k < KSLOT; ++k) minv[k] = INF_;
        unsigned int used = 0;
        int j0 = Q_;
        float uicur = u[isrc];

        float pre[KSLOT];
        {
            const float* __restrict__ row = cb + (size_t)isrc * Q_;
            #pragma unroll
            for (int k = 0; k < KSLOT; ++k) {
                int j = k * 64 + lane;
                pre[k] = (j < Q_) ? row[j] : INF_;
            }
        }

        int jfin;
        while (true) {
            // scan current row (data in pre), relax minv/way, local argmin
            float best = INF_; int bj = Q_;
            #pragma unroll
            for (int k = 0; k < KSLOT; ++k) {
                int j = k * 64 + lane;
                if (j < Q_ && !((used >> k) & 1u)) {
                    float cur = pre[k] - uicur - v[k];
                    if (cur < minv[k]) { minv[k] = cur; way[j] = j0; }
                    float mm = minv[k];
                    if (mm < best) { best = mm; bj = j; }
                }
            }
            #pragma unroll
            for (int off = 1; off < 64; off <<= 1) {
                float ov = __shfl_xor(best, off, 64);
                int   oj = __shfl_xor(bj,   off, 64);
                if (ov < best || (ov == best && oj < bj)) { best = ov; bj = oj; }
            }
            const float delta = best;      // uniform after butterfly
            const int   j1    = bj;
            const int   inext = p[j1];     // early read (uniform addr)

            // speculative prefetch of next row (clamped; discarded on break)
            {
                int ipre = (inext < 0) ? 0 : inext;
                const float* __restrict__ row = cb + (size_t)ipre * Q_;
                #pragma unroll
                for (int k = 0; k < KSLOT; ++k) {
                    int j = k * 64 + lane;
                    pre[k] = (j < Q_) ? row[j] : INF_;
                }
            }

            // dual updates under the load shadow (j1 counted FREE here,
            // exactly like the reference/round 3)
            if (lane == 0) u[isrc] = u[isrc] + delta;
            #pragma unroll
            for (int k = 0; k < KSLOT; ++k) {
                int j = k * 64 + lane;
                if (j < Q_) {
                    if ((used >> k) & 1u) {
                        int r = p[j];            // distinct rows per used col
                        u[r] = u[r] + delta;     // distinct addrs: no race
                        v[k] -= delta;
                    } else {
                        minv[k] -= delta;
                    }
                }
            }

            if (inext < 0) { jfin = j1; break; }

            if (lane == (j1 & 63)) used |= 1u << (j1 >> 6);
            float tsel = (inext < 64) ? u_lo : u_hi;   // inext uniform
            uicur = __shfl(tsel, inext & 63, 64);      // tree-start value: exact
            j0 = j1;
        }

        // augment along predecessor chain (lane 0; DS in-order per wave)
        if (lane == 0) {
            int jj = jfin;
            while (true) {
                int jp = way[jj];
                if (jp == Q_) { p[jj] = isrc; break; }
                p[jj] = p[jp];
                jj = jp;
            }
        }
        __syncthreads();
    }

    // ---- outputs: col[t] = assigned query; rank-sort ascending by query ----
    #pragma unroll
    for (int k = 0; k < KSLOT; ++k) {
        int j = k * 64 + lane;
        if (j < Q_) {
            int r = p[j];
            if (r >= 0) col[r] = j;
        }
    }
    __syncthreads();
    for (int t = lane; t < T_; t += 64) {
        int cj = col[t];
        int rank = 0;
        for (int t2 = 0; t2 < T_; ++t2) rank += (col[t2] < cj) ? 1 : 0;
        out_pred[b * T_ + rank] = (float)cj;
        out_tgt [b * T_ + rank] = (float)t;
    }
}

extern "C" void kernel_launch(void* const* d_in, const int* in_sizes, int n_in,
                              void* d_out, int out_size, void* d_ws, size_t ws_size,
                              hipStream_t stream) {
    const float* logits  = (const float*)d_in[0];   // [B,Q,C]
    const float* pboxes  = (const float*)d_in[1];   // [B,Q,4]
    const int*   tlabels = (const int*)d_in[2];     // [B,T]
    const float* tboxes  = (const float*)d_in[3];   // [B,T,4]

    float* out      = (float*)d_out;
    float* cost     = out;                                   // [B,Q,T]
    float* out_pred = out + (size_t)B_ * Q_ * T_;            // [B,T]
    float* out_tgt  = out_pred + (size_t)B_ * T_;            // [B,T]

    float* costT = (float*)d_ws;  // [B,T,Q]; ws >= 23 MB proven in round 4

    dim3 gridc(4, NTC, B_);
    cost_kernel<<<gridc, 256, 0, stream>>>(logits, pboxes, tlabels, tboxes, cost, costT);
    hung_kernel<<<B_, 64, 0, stream>>>(costT, out_pred, out_tgt);
}

// Round 6
// 290.064 us; speedup vs baseline: 1.2530x; 1.2530x over previous
//
#include <hip/hip_runtime.h>
#include <stdint.h>

#define B_ 64
#define Q_ 900
#define T_ 100
#define C_ 256
#define INF_ 1e9f
#define TCH 20      // targets per cost-kernel chunk
#define NTC 5       // T_/TCH
#define KSLOT 15    // ceil(Q_/64) column slots per lane in hung kernel
#define RG 4        // rows per warm-start group (T_ % RG == 0)

// ---------------------------------------------------------------------------
// Wave64 min-reductions via DPP (VALU, ~10x faster than ds_bpermute shuffles).
// Sequence: row_shr 1/2/4/8 (row minima in lane 15 of each 16-row), then
// row_bcast15 (rows 1,3) and row_bcast31 (rows 2,3) -> lane 63 = global min.
// old = identity so invalid/unwritten lanes contribute the identity.
// ---------------------------------------------------------------------------
#define DPP_STEP_F(x, ctrl, rmask)                                             \
    x = fminf(x, __int_as_float(__builtin_amdgcn_update_dpp(                   \
            0x7F800000 /*+inf*/, __float_as_int(x), ctrl, rmask, 0xF, false)))
#define DPP_STEP_I(x, ctrl, rmask)                                             \
    x = min(x, __builtin_amdgcn_update_dpp(                                    \
            0x7FFFFFFF, x, ctrl, rmask, 0xF, false))

__device__ __forceinline__ float wave_min_bcast_f(float x) {
    DPP_STEP_F(x, 0x111, 0xF);   // row_shr:1
    DPP_STEP_F(x, 0x112, 0xF);   // row_shr:2
    DPP_STEP_F(x, 0x114, 0xF);   // row_shr:4
    DPP_STEP_F(x, 0x118, 0xF);   // row_shr:8
    DPP_STEP_F(x, 0x142, 0xA);   // row_bcast:15 -> rows 1,3
    DPP_STEP_F(x, 0x143, 0xC);   // row_bcast:31 -> rows 2,3
    return __int_as_float(__builtin_amdgcn_readlane(__float_as_int(x), 63));
}
__device__ __forceinline__ int wave_min_bcast_i(int x) {
    DPP_STEP_I(x, 0x111, 0xF);
    DPP_STEP_I(x, 0x112, 0xF);
    DPP_STEP_I(x, 0x114, 0xF);
    DPP_STEP_I(x, 0x118, 0xF);
    DPP_STEP_I(x, 0x142, 0xA);
    DPP_STEP_I(x, 0x143, 0xC);
    return __builtin_amdgcn_readlane(x, 63);
}

// ---------------------------------------------------------------------------
// Kernel 1: cost matrix, t-chunked for occupancy.
// ---------------------------------------------------------------------------
__global__ __launch_bounds__(256) void cost_kernel(
    const float* __restrict__ logits,   // [B,Q,C]
    const float* __restrict__ pboxes,   // [B,Q,4] cxcywh
    const int*   __restrict__ tlabels,  // [B,T]
    const float* __restrict__ tboxes,   // [B,T,4] cxcywh
    float* __restrict__ cost_out,       // [B,Q,T]
    float* __restrict__ costT_out)      // [B,T,Q]
{
    const int b   = blockIdx.z;
    const int t0  = blockIdx.y * TCH;
    const int tid = threadIdx.x;
    const int q   = blockIdx.x * 256 + tid;

    __shared__ float s_cx[TCH][4];
    __shared__ float s_xy[TCH][4];
    __shared__ float s_area[TCH];
    __shared__ int   s_lab[TCH];

    for (int t = tid; t < TCH; t += 256) {
        const float4 tb = *reinterpret_cast<const float4*>(tboxes + ((size_t)b * T_ + t0 + t) * 4);
        float cx = tb.x, cy = tb.y, w = tb.z, h = tb.w;
        s_cx[t][0] = cx; s_cx[t][1] = cy; s_cx[t][2] = w; s_cx[t][3] = h;
        float x0 = cx - 0.5f * w, y0 = cy - 0.5f * h;
        float x1 = cx + 0.5f * w, y1 = cy + 0.5f * h;
        s_xy[t][0] = x0; s_xy[t][1] = y0; s_xy[t][2] = x1; s_xy[t][3] = y1;
        s_area[t] = (x1 - x0) * (y1 - y0);
        s_lab[t]  = tlabels[b * T_ + t0 + t];
    }
    __syncthreads();
    if (q >= Q_) return;

    const float4 pb = *reinterpret_cast<const float4*>(pboxes + ((size_t)b * Q_ + q) * 4);
    const float pcx = pb.x, pcy = pb.y, pw = pb.z, ph = pb.w;
    const float ax0 = pcx - 0.5f * pw, ay0 = pcy - 0.5f * ph;
    const float ax1 = pcx + 0.5f * pw, ay1 = pcy + 0.5f * ph;
    const float area_a = (ax1 - ax0) * (ay1 - ay0);
    const float* __restrict__ lrow = logits + ((size_t)b * Q_ + q) * C_;

    float c[TCH];
    #pragma unroll
    for (int tt = 0; tt < TCH; ++tt) {
        float cls = -lrow[s_lab[tt]];
        float l1 = fabsf(pcx - s_cx[tt][0]) + fabsf(pcy - s_cx[tt][1])
                 + fabsf(pw  - s_cx[tt][2]) + fabsf(ph  - s_cx[tt][3]);
        float bx0 = s_xy[tt][0], by0 = s_xy[tt][1], bx1 = s_xy[tt][2], by1 = s_xy[tt][3];
        float ltx = fmaxf(ax0, bx0), lty = fmaxf(ay0, by0);
        float rbx = fminf(ax1, bx1), rby = fminf(ay1, by1);
        float wx = fmaxf(rbx - ltx, 0.0f), wy = fmaxf(rby - lty, 0.0f);
        float inter = wx * wy;
        float uni = area_a + s_area[tt] - inter;
        float iou = inter / uni;
        float ex0 = fminf(ax0, bx0), ey0 = fminf(ay0, by0);
        float ex1 = fmaxf(ax1, bx1), ey1 = fmaxf(ay1, by1);
        float ew = fmaxf(ex1 - ex0, 0.0f), eh = fmaxf(ey1 - ey0, 0.0f);
        float enc = ew * eh;
        float giou = iou - (enc - uni) / enc;
        c[tt] = cls + l1 - giou;
    }

    float* __restrict__ ct = costT_out + (size_t)b * T_ * Q_ + (size_t)t0 * Q_ + q;
    #pragma unroll
    for (int tt = 0; tt < TCH; ++tt) ct[(size_t)tt * Q_] = c[tt];

    float4* __restrict__ orow = reinterpret_cast<float4*>(cost_out + ((size_t)b * Q_ + q) * T_ + t0);
    #pragma unroll
    for (int t4 = 0; t4 < TCH / 4; ++t4)
        orow[t4] = make_float4(c[4*t4], c[4*t4+1], c[4*t4+2], c[4*t4+3]);
}

// ---------------------------------------------------------------------------
// Kernel 2: exact Hungarian (JV SAP), one wave per batch.
// u = row minima, v = 0 (proven arithmetic); DPP reductions on the critical
// path; wave-synchronous inner loop (no barriers); non-volatile LDS (barriers
// at tree boundaries provide ordering; p[] is loop-invariant inside a tree).
// ---------------------------------------------------------------------------
__global__ __launch_bounds__(64) void hung_kernel(
    const float* __restrict__ costT,   // [B,T,Q]
    float* __restrict__ out_pred,      // [B,T] as float
    float* __restrict__ out_tgt)       // [B,T] as float
{
    const int b = blockIdx.x;
    const int lane = threadIdx.x;
    const float* __restrict__ cb = costT + (size_t)b * T_ * Q_;

    __shared__ float u[128];           // padded so u[64+lane] is in-bounds
    __shared__ int   p[Q_];
    __shared__ int   way[Q_];          // also greedy scratch before SAP
    __shared__ int   ji[T_];
    __shared__ int   pend[T_];
    __shared__ int   col[T_];

    float v[KSLOT], minv[KSLOT];

    #pragma unroll
    for (int k = 0; k < KSLOT; ++k) {
        int j = k * 64 + lane;
        if (j < Q_) { p[j] = -1; way[j] = 0x7FFFFFFF; }
        v[k] = 0.0f;
    }
    if (lane < 28) u[100 + lane] = INF_;   // pad region defined

    // ---- warm start: u[i] = row min, ji[i] = first argmin ----
    for (int g = 0; g < T_; g += RG) {
        float rv[RG][KSLOT];
        #pragma unroll
        for (int r = 0; r < RG; ++r) {
            const float* __restrict__ row = cb + (size_t)(g + r) * Q_;
            #pragma unroll
            for (int k = 0; k < KSLOT; ++k) {
                int j = k * 64 + lane;
                rv[r][k] = (j < Q_) ? row[j] : INF_;
            }
        }
        #pragma unroll
        for (int r = 0; r < RG; ++r) {
            float m = INF_; int mj = Q_;
            #pragma unroll
            for (int k = 0; k < KSLOT; ++k) {
                int j = k * 64 + lane;
                if (rv[r][k] < m) { m = rv[r][k]; mj = j; }   // strict <: first index
            }
            const float mm = wave_min_bcast_f(m);
            const int   gj = wave_min_bcast_i((m == mm) ? mj : 0x7FFFFFFF);
            if (lane == 0) { u[g + r] = mm; ji[g + r] = gj; }
        }
    }
    __syncthreads();

    // ---- parallel greedy: column winner = smallest suitor row ----
    {
        int t0 = lane, t1 = lane + 64;
        if (t0 < T_) atomicMin(&way[ji[t0]], t0);
        if (t1 < T_) atomicMin(&way[ji[t1]], t1);
    }
    __syncthreads();
    bool lose0 = false, lose1 = false;
    {
        int t0 = lane, t1 = lane + 64;
        if (t0 < T_) {
            int j = ji[t0];
            if (way[j] == t0) p[j] = t0; else lose0 = true;
        }
        if (t1 < T_) {
            int j = ji[t1];
            if (way[j] == t1) p[j] = t1; else lose1 = true;
        }
    }
    unsigned long long m0 = __ballot(lose0);
    unsigned long long m1 = __ballot(lose1);
    const int c0 = __popcll(m0);
    if (lose0) pend[__popcll(m0 & ((1ull << lane) - 1ull))] = lane;
    if (lose1) pend[c0 + __popcll(m1 & ((1ull << lane) - 1ull))] = lane + 64;
    const int npend = c0 + __popcll(m1);
    __syncthreads();

    // ---- SAP per pending row (barrier-free inner loop) ----
    for (int kk = 0; kk < npend; ++kk) {
        const int isrc = pend[kk];
        const float u_lo = u[lane];        // tree-start snapshot (rows enter once)
        const float u_hi = u[64 + lane];
        #pragma unroll
        for (int k = 0; k < KSLOT; ++k) minv[k] = INF_;
        unsigned int used = 0;
        int j0 = Q_;
        float uicur = u[isrc];

        float pre[KSLOT];
        {
            const float* __restrict__ row = cb + (size_t)isrc * Q_;
            #pragma unroll
            for (int k = 0; k < KSLOT; ++k) {
                int j = k * 64 + lane;
                pre[k] = (j < Q_) ? row[j] : INF_;
            }
        }

        int jfin;
        while (true) {
            // scan current row (in pre), relax minv/way, per-lane argmin
            float best = INF_; int bj = Q_;
            #pragma unroll
            for (int k = 0; k < KSLOT; ++k) {
                int j = k * 64 + lane;
                if (j < Q_ && !((used >> k) & 1u)) {
                    float cur = pre[k] - uicur - v[k];
                    if (cur < minv[k]) { minv[k] = cur; way[j] = j0; }
                    float mm = minv[k];
                    if (mm < best) { best = mm; bj = j; }
                }
            }
            const float delta = wave_min_bcast_f(best);                       // uniform
            const int   j1    = wave_min_bcast_i((best == delta) ? bj : 0x7FFFFFFF);
            const int   inext = p[j1];     // uniform addr LDS read

            // speculative prefetch of next row (clamped; discarded on break)
            {
                int ipre = (inext < 0) ? 0 : inext;
                const float* __restrict__ row = cb + (size_t)ipre * Q_;
                #pragma unroll
                for (int k = 0; k < KSLOT; ++k) {
                    int j = k * 64 + lane;
                    pre[k] = (j < Q_) ? row[j] : INF_;
                }
            }

            // dual updates under the load shadow (j1 counted FREE here,
            // exactly like the reference)
            if (lane == 0) u[isrc] = u[isrc] + delta;
            #pragma unroll
            for (int k = 0; k < KSLOT; ++k) {
                int j = k * 64 + lane;
                if (j < Q_) {
                    if ((used >> k) & 1u) {
                        int r = p[j];            // distinct rows per used col
                        u[r] = u[r] + delta;     // distinct addrs: no race
                        v[k] -= delta;
                    } else {
                        minv[k] -= delta;
                    }
                }
            }

            if (inext < 0) { jfin = j1; break; }

            if (lane == (j1 & 63)) used |= 1u << (j1 >> 6);
            {
                const int si = __builtin_amdgcn_readfirstlane(inext);
                const float tsel = (si < 64) ? u_lo : u_hi;      // uniform branch
                uicur = __int_as_float(
                    __builtin_amdgcn_readlane(__float_as_int(tsel), si & 63));
            }
            j0 = j1;
        }

        // augment along predecessor chain (lane 0; DS ops in-order per wave)
        if (lane == 0) {
            int jj = jfin;
            while (true) {
                int jp = way[jj];
                if (jp == Q_) { p[jj] = isrc; break; }
                p[jj] = p[jp];
                jj = jp;
            }
        }
        __syncthreads();
    }

    // ---- outputs: col[t] = assigned query; rank-sort ascending by query ----
    #pragma unroll
    for (int k = 0; k < KSLOT; ++k) {
        int j = k * 64 + lane;
        if (j < Q_) {
            int r = p[j];
            if (r >= 0) col[r] = j;
        }
    }
    __syncthreads();
    for (int t = lane; t < T_; t += 64) {
        int cj = col[t];
        int rank = 0;
        for (int t2 = 0; t2 < T_; ++t2) rank += (col[t2] < cj) ? 1 : 0;
        out_pred[b * T_ + rank] = (float)cj;
        out_tgt [b * T_ + rank] = (float)t;
    }
}

extern "C" void kernel_launch(void* const* d_in, const int* in_sizes, int n_in,
                              void* d_out, int out_size, void* d_ws, size_t ws_size,
                              hipStream_t stream) {
    const float* logits  = (const float*)d_in[0];   // [B,Q,C]
    const float* pboxes  = (const float*)d_in[1];   // [B,Q,4]
    const int*   tlabels = (const int*)d_in[2];     // [B,T]
    const float* tboxes  = (const float*)d_in[3];   // [B,T,4]

    float* out      = (float*)d_out;
    float* cost     = out;                                   // [B,Q,T]
    float* out_pred = out + (size_t)B_ * Q_ * T_;            // [B,T]
    float* out_tgt  = out_pred + (size_t)B_ * T_;            // [B,T]

    float* costT = (float*)d_ws;  // [B,T,Q]; ws >= 23 MB proven in round 4

    dim3 gridc(4, NTC, B_);
    cost_kernel<<<gridc, 256, 0, stream>>>(logits, pboxes, tlabels, tboxes, cost, costT);
    hung_kernel<<<B_, 64, 0, stream>>>(costT, out_pred, out_tgt);
}

// Round 7
// 193.032 us; speedup vs baseline: 1.8829x; 1.5027x over previous
//
#include <hip/hip_runtime.h>
#include <stdint.h>

#define B_ 64
#define Q_ 900
#define T_ 100
#define C_ 256
#define INF_ 1e9f
#define TCH 20      // targets per cost-kernel chunk
#define NTC 5       // T_/TCH
#define KSLOT 15    // ceil(Q_/64) column slots per lane
#define RG 4        // rows per warm-start group
#define NW 4        // waves per hung block (parallel trees)

// ---------------------------------------------------------------------------
// Wave64 min-reductions via DPP (verified on HW in round 6).
// ---------------------------------------------------------------------------
#define DPP_STEP_F(x, ctrl, rmask)                                             \
    x = fminf(x, __int_as_float(__builtin_amdgcn_update_dpp(                   \
            0x7F800000 /*+inf*/, __float_as_int(x), ctrl, rmask, 0xF, false)))
#define DPP_STEP_I(x, ctrl, rmask)                                             \
    x = min(x, __builtin_amdgcn_update_dpp(                                    \
            0x7FFFFFFF, x, ctrl, rmask, 0xF, false))

__device__ __forceinline__ float wave_min_bcast_f(float x) {
    DPP_STEP_F(x, 0x111, 0xF);   // row_shr:1
    DPP_STEP_F(x, 0x112, 0xF);   // row_shr:2
    DPP_STEP_F(x, 0x114, 0xF);   // row_shr:4
    DPP_STEP_F(x, 0x118, 0xF);   // row_shr:8
    DPP_STEP_F(x, 0x142, 0xA);   // row_bcast:15 -> rows 1,3
    DPP_STEP_F(x, 0x143, 0xC);   // row_bcast:31 -> rows 2,3
    return __int_as_float(__builtin_amdgcn_readlane(__float_as_int(x), 63));
}
__device__ __forceinline__ int wave_min_bcast_i(int x) {
    DPP_STEP_I(x, 0x111, 0xF);
    DPP_STEP_I(x, 0x112, 0xF);
    DPP_STEP_I(x, 0x114, 0xF);
    DPP_STEP_I(x, 0x118, 0xF);
    DPP_STEP_I(x, 0x142, 0xA);
    DPP_STEP_I(x, 0x143, 0xC);
    return __builtin_amdgcn_readlane(x, 63);
}

// ---------------------------------------------------------------------------
// Kernel 1: cost matrix (unchanged from round 6).
// ---------------------------------------------------------------------------
__global__ __launch_bounds__(256) void cost_kernel(
    const float* __restrict__ logits,   // [B,Q,C]
    const float* __restrict__ pboxes,   // [B,Q,4] cxcywh
    const int*   __restrict__ tlabels,  // [B,T]
    const float* __restrict__ tboxes,   // [B,T,4] cxcywh
    float* __restrict__ cost_out,       // [B,Q,T]
    float* __restrict__ costT_out)      // [B,T,Q]
{
    const int b   = blockIdx.z;
    const int t0  = blockIdx.y * TCH;
    const int tid = threadIdx.x;
    const int q   = blockIdx.x * 256 + tid;

    __shared__ float s_cx[TCH][4];
    __shared__ float s_xy[TCH][4];
    __shared__ float s_area[TCH];
    __shared__ int   s_lab[TCH];

    for (int t = tid; t < TCH; t += 256) {
        const float4 tb = *reinterpret_cast<const float4*>(tboxes + ((size_t)b * T_ + t0 + t) * 4);
        float cx = tb.x, cy = tb.y, w = tb.z, h = tb.w;
        s_cx[t][0] = cx; s_cx[t][1] = cy; s_cx[t][2] = w; s_cx[t][3] = h;
        float x0 = cx - 0.5f * w, y0 = cy - 0.5f * h;
        float x1 = cx + 0.5f * w, y1 = cy + 0.5f * h;
        s_xy[t][0] = x0; s_xy[t][1] = y0; s_xy[t][2] = x1; s_xy[t][3] = y1;
        s_area[t] = (x1 - x0) * (y1 - y0);
        s_lab[t]  = tlabels[b * T_ + t0 + t];
    }
    __syncthreads();
    if (q >= Q_) return;

    const float4 pb = *reinterpret_cast<const float4*>(pboxes + ((size_t)b * Q_ + q) * 4);
    const float pcx = pb.x, pcy = pb.y, pw = pb.z, ph = pb.w;
    const float ax0 = pcx - 0.5f * pw, ay0 = pcy - 0.5f * ph;
    const float ax1 = pcx + 0.5f * pw, ay1 = pcy + 0.5f * ph;
    const float area_a = (ax1 - ax0) * (ay1 - ay0);
    const float* __restrict__ lrow = logits + ((size_t)b * Q_ + q) * C_;

    float c[TCH];
    #pragma unroll
    for (int tt = 0; tt < TCH; ++tt) {
        float cls = -lrow[s_lab[tt]];
        float l1 = fabsf(pcx - s_cx[tt][0]) + fabsf(pcy - s_cx[tt][1])
                 + fabsf(pw  - s_cx[tt][2]) + fabsf(ph  - s_cx[tt][3]);
        float bx0 = s_xy[tt][0], by0 = s_xy[tt][1], bx1 = s_xy[tt][2], by1 = s_xy[tt][3];
        float ltx = fmaxf(ax0, bx0), lty = fmaxf(ay0, by0);
        float rbx = fminf(ax1, bx1), rby = fminf(ay1, by1);
        float wx = fmaxf(rbx - ltx, 0.0f), wy = fmaxf(rby - lty, 0.0f);
        float inter = wx * wy;
        float uni = area_a + s_area[tt] - inter;
        float iou = inter / uni;
        float ex0 = fminf(ax0, bx0), ey0 = fminf(ay0, by0);
        float ex1 = fmaxf(ax1, bx1), ey1 = fmaxf(ay1, by1);
        float ew = fmaxf(ex1 - ex0, 0.0f), eh = fmaxf(ey1 - ey0, 0.0f);
        float enc = ew * eh;
        float giou = iou - (enc - uni) / enc;
        c[tt] = cls + l1 - giou;
    }

    float* __restrict__ ct = costT_out + (size_t)b * T_ * Q_ + (size_t)t0 * Q_ + q;
    #pragma unroll
    for (int tt = 0; tt < TCH; ++tt) ct[(size_t)tt * Q_] = c[tt];

    float4* __restrict__ orow = reinterpret_cast<float4*>(cost_out + ((size_t)b * Q_ + q) * T_ + t0);
    #pragma unroll
    for (int t4 = 0; t4 < TCH / 4; ++t4)
        orow[t4] = make_float4(c[4*t4], c[4*t4+1], c[4*t4+2], c[4*t4+3]);
}

// ---------------------------------------------------------------------------
// Kernel 2: exact Hungarian, NW=4 speculatively-parallel SAP trees per batch.
// Each wave runs a private JV tree vs the committed snapshot; trees commit
// only if their column sets are pairwise disjoint (checked by mask AND);
// rejected trees rerun. JV is processing-order-independent and the optimum
// is a.s. unique => exact, matches reference. Duals stay generic (v=0 start,
// u=row minima) — no manufactured exact ties.
// ---------------------------------------------------------------------------
__global__ __launch_bounds__(256) void hung_kernel(
    const float* __restrict__ costT,   // [B,T,Q]
    float* __restrict__ out_pred,      // [B,T] as float
    float* __restrict__ out_tgt)       // [B,T] as float
{
    const int b    = blockIdx.x;
    const int tid  = threadIdx.x;
    const int lane = tid & 63;
    const int wave = tid >> 6;
    const float* __restrict__ cb = costT + (size_t)b * T_ * Q_;

    __shared__ float u[128];             // [100] + pad for snapshot reads
    __shared__ float v[Q_];              // committed column duals
    __shared__ int   p[Q_];              // committed matching (col -> row)
    __shared__ int   way_priv[NW][Q_];   // per-wave predecessor arrays
    __shared__ int   ji[T_];
    __shared__ int   s_pend[T_];
    __shared__ int   col[T_];
    __shared__ int   s_mask[NW][64];     // per-wave tree column masks
    __shared__ int   s_qn, s_acc;

    // ---- init committed state ----
    for (int j = tid; j < Q_; j += 256) {
        p[j] = -1; v[j] = 0.0f; way_priv[0][j] = 0x7FFFFFFF;  // [0] = greedy scratch
    }
    if (tid >= 100 && tid < 128) u[tid] = INF_;

    // ---- warm start: u[i] = row min, ji[i] = first argmin (4 waves) ----
    for (int g = wave * RG; g < T_; g += NW * RG) {
        float rv[RG][KSLOT];
        #pragma unroll
        for (int r = 0; r < RG; ++r) {
            const float* __restrict__ row = cb + (size_t)(g + r) * Q_;
            #pragma unroll
            for (int k = 0; k < KSLOT; ++k) {
                int j = k * 64 + lane;
                rv[r][k] = (j < Q_) ? row[j] : INF_;
            }
        }
        #pragma unroll
        for (int r = 0; r < RG; ++r) {
            float m = INF_; int mj = Q_;
            #pragma unroll
            for (int k = 0; k < KSLOT; ++k) {
                int j = k * 64 + lane;
                if (rv[r][k] < m) { m = rv[r][k]; mj = j; }   // strict <: first index
            }
            const float mm = wave_min_bcast_f(m);
            const int   gj = wave_min_bcast_i((m == mm) ? mj : 0x7FFFFFFF);
            if (lane == 0) { u[g + r] = mm; ji[g + r] = gj; }
        }
    }
    __syncthreads();

    // ---- parallel greedy (wave 0): column winner = smallest suitor row ----
    if (wave == 0) {
        int t0 = lane, t1 = lane + 64;
        if (t0 < T_) atomicMin(&way_priv[0][ji[t0]], t0);
        if (t1 < T_) atomicMin(&way_priv[0][ji[t1]], t1);
        bool lose0 = false, lose1 = false;
        if (t0 < T_) {
            int j = ji[t0];
            if (way_priv[0][j] == t0) p[j] = t0; else lose0 = true;
        }
        if (t1 < T_) {
            int j = ji[t1];
            if (way_priv[0][j] == t1) p[j] = t1; else lose1 = true;
        }
        unsigned long long m0 = __ballot(lose0);
        unsigned long long m1 = __ballot(lose1);
        const int c0 = __popcll(m0);
        if (lose0) s_pend[__popcll(m0 & ((1ull << lane) - 1ull))] = lane;
        if (lose1) s_pend[c0 + __popcll(m1 & ((1ull << lane) - 1ull))] = lane + 64;
        if (lane == 0) s_qn = c0 + __popcll(m1);
    }

    // ---- super-iterations: up to NW speculative trees, disjoint-commit ----
    for (;;) {
        __syncthreads();                    // commits + queue visible
        const int qn = s_qn;
        if (qn <= 0) break;
        const int nact   = (qn < NW) ? qn : NW;
        const bool active = (wave < nact);
        const int  isrc   = active ? s_pend[wave] : -1;

        // committed snapshots (stable this super-iteration)
        const float u_lo = u[lane];
        const float u_hi = u[64 + lane];
        float vreg[KSLOT];
        #pragma unroll
        for (int k = 0; k < KSLOT; ++k) {
            int j = k * 64 + lane;
            vreg[k] = (j < Q_) ? v[j] : 0.0f;
        }

        unsigned int used = 0;
        float vadd[KSLOT], minv[KSLOT];
        float uisrc_acc = 0.0f;
        int jfin = Q_;

        if (active) {
            int* __restrict__ wayw = way_priv[wave];
            #pragma unroll
            for (int k = 0; k < KSLOT; ++k) { minv[k] = INF_; vadd[k] = 0.0f; }
            int j0 = Q_;
            uisrc_acc = u[isrc];
            float uicur = uisrc_acc;

            float pre[KSLOT];
            {
                const float* __restrict__ row = cb + (size_t)isrc * Q_;
                #pragma unroll
                for (int k = 0; k < KSLOT; ++k) {
                    int j = k * 64 + lane;
                    pre[k] = (j < Q_) ? row[j] : INF_;
                }
            }

            while (true) {
                float best = INF_; int bj = Q_;
                #pragma unroll
                for (int k = 0; k < KSLOT; ++k) {
                    int j = k * 64 + lane;
                    if (j < Q_ && !((used >> k) & 1u)) {
                        float cur = pre[k] - uicur - vreg[k];
                        if (cur < minv[k]) { minv[k] = cur; wayw[j] = j0; }
                        float mm = minv[k];
                        if (mm < best) { best = mm; bj = j; }
                    }
                }
                const float delta = wave_min_bcast_f(best);
                const int   j1    = wave_min_bcast_i((best == delta) ? bj : 0x7FFFFFFF);
                const int   inext = p[j1];          // committed (stable)

                // speculative prefetch of next row
                {
                    int ipre = (inext < 0) ? 0 : inext;
                    const float* __restrict__ row = cb + (size_t)ipre * Q_;
                    #pragma unroll
                    for (int k = 0; k < KSLOT; ++k) {
                        int j = k * 64 + lane;
                        pre[k] = (j < Q_) ? row[j] : INF_;
                    }
                }

                // dual updates (j1 counted FREE here, as reference/r6)
                uisrc_acc += delta;
                #pragma unroll
                for (int k = 0; k < KSLOT; ++k) {
                    int j = k * 64 + lane;
                    if (j < Q_) {
                        if ((used >> k) & 1u) vadd[k] += delta;
                        else                  minv[k] -= delta;
                    }
                }

                if (inext < 0) { jfin = j1; break; }

                if (lane == (j1 & 63)) used |= 1u << (j1 >> 6);
                {
                    const int si = __builtin_amdgcn_readfirstlane(inext);
                    const float tsel = (si < 64) ? u_lo : u_hi;
                    uicur = __int_as_float(
                        __builtin_amdgcn_readlane(__float_as_int(tsel), si & 63));
                }
                j0 = j1;
            }
        }

        // publish tree column mask (used cols + final col)
        {
            int msk = active ? (int)used : 0;
            if (active && lane == (jfin & 63)) msk |= 1 << (jfin >> 6);
            s_mask[wave][lane] = msk;
        }
        __syncthreads();

        // acceptance: greedy prefix in pend order, pairwise disjoint (wave 0)
        if (wave == 0) {
            int acc = 1;
            for (int bb = 1; bb < nact; ++bb) {
                int mb = s_mask[bb][lane];
                bool ok = true;
                for (int aa = 0; aa < bb; ++aa) {
                    if ((acc >> aa) & 1) {
                        bool hit = (s_mask[aa][lane] & mb) != 0;
                        if (__ballot(hit) != 0ull) ok = false;
                    }
                }
                if (ok) acc |= 1 << bb;
            }
            if (lane == 0) s_acc = acc;
        }
        __syncthreads();

        // commit accepted trees (disjoint => parallel-safe)
        if (active && ((s_acc >> wave) & 1)) {
            #pragma unroll
            for (int k = 0; k < KSLOT; ++k) {
                int j = k * 64 + lane;
                if (j < Q_ && ((used >> k) & 1u)) {
                    int r = p[j];                  // row matched to j (pre-augment)
                    u[r] = u[r] + vadd[k];
                    v[j] = v[j] - vadd[k];
                }
            }
            if (lane == 0) {
                u[isrc] = uisrc_acc;
                int jj = jfin;
                int* __restrict__ wayw = way_priv[wave];
                while (true) {
                    int jp = wayw[jj];
                    if (jp == Q_) { p[jj] = isrc; break; }
                    p[jj] = p[jp];
                    jj = jp;
                }
            }
        }
        __syncthreads();

        // rebuild queue (rejected keep order, go to front)
        if (tid == 0) {
            int acc = s_acc;
            int tmp[NW]; int nrej = 0;
            for (int w = 0; w < nact; ++w)
                if (!((acc >> w) & 1)) tmp[nrej++] = s_pend[w];
            for (int i = 0; i < nrej; ++i) s_pend[i] = tmp[i];
            for (int i = nact; i < qn; ++i) s_pend[nrej + i - nact] = s_pend[i];
            s_qn = qn - nact + nrej;
        }
    }

    // ---- outputs: col[t] = assigned query; rank-sort ascending by query ----
    for (int j = tid; j < Q_; j += 256) {
        int r = p[j];
        if (r >= 0) col[r] = j;
    }
    __syncthreads();
    if (tid < T_) {
        int cj = col[tid];
        int rank = 0;
        for (int t2 = 0; t2 < T_; ++t2) rank += (col[t2] < cj) ? 1 : 0;
        out_pred[b * T_ + rank] = (float)cj;
        out_tgt [b * T_ + rank] = (float)tid;
    }
}

extern "C" void kernel_launch(void* const* d_in, const int* in_sizes, int n_in,
                              void* d_out, int out_size, void* d_ws, size_t ws_size,
                              hipStream_t stream) {
    const float* logits  = (const float*)d_in[0];   // [B,Q,C]
    const float* pboxes  = (const float*)d_in[1];   // [B,Q,4]
    const int*   tlabels = (const int*)d_in[2];     // [B,T]
    const float* tboxes  = (const float*)d_in[3];   // [B,T,4]

    float* out      = (float*)d_out;
    float* cost     = out;                                   // [B,Q,T]
    float* out_pred = out + (size_t)B_ * Q_ * T_;            // [B,T]
    float* out_tgt  = out_pred + (size_t)B_ * T_;            // [B,T]

    float* costT = (float*)d_ws;  // [B,T,Q]; ws >= 23 MB proven

    dim3 gridc(4, NTC, B_);
    cost_kernel<<<gridc, 256, 0, stream>>>(logits, pboxes, tlabels, tboxes, cost, costT);
    hung_kernel<<<B_, 256, 0, stream>>>(costT, out_pred, out_tgt);
}